// Round 14
// baseline (411.218 us; speedup 1.0000x reference)
//
#include <hip/hip_runtime.h>

typedef unsigned short u16;
typedef unsigned int u32;

#define N_NODES 50000
#define N_EDGES 1600000
#define CH 128
#define CHW 64          // u32 words per packed-bf16 row
#define NG 512
#define CAP 128         // bucket capacity per node (Poisson(32): P(>=128) ~ 1e-43)
#define PAD 136         // LDS row stride in bf16 elems (272B: 16B-aligned, bank-spread)
#define NBINS 196       // ceil(50000/256)
#define BINCAP 12288    // slots per bin (expect ~8192, max ~8650)
#define NSCAT 1024      // scatter workgroups
#define ECHUNK 1563     // edges per scatter WG (1024*1563 >= 1.6M)

typedef __bf16 bf16x8 __attribute__((ext_vector_type(8)));
typedef float f32x4 __attribute__((ext_vector_type(4)));

// ---- workspace byte offsets (total ~51.6 MB) ----
#define OFF_DEG 0ull
#define OFF_BUCKET 200192ull      // u16 bucket, 12,800,000 B
#define OFF_XB 13000192ull        // 12.8 MB packed-bf16 x; reused as h2
#define OFF_HSUM 25800192ull      // 12.8 MB; binned edges (9.6 MB) overlap pre-agg
#define OFF_H1 38600192ull        // 12.8 MB
#define OFF_GS 51400192ull        // 2,048 B
#define OFF_GE 51402240ull        // 2,048 B (gend + binCursor contiguous: one memset)
#define OFF_BCUR 51404288ull      // 1,024 B
#define OFF_WT 51405312ull        // 4 x 32,768 B bf16 transposed weights [n][k]
#define OFF_BC 51536384ull        // 4 x 512 B fp32 biases
#define OFF_WF1 51538432ull       // 65,536 B fp32
#define OFF_BF1 51603968ull       // 512 B
#define OFF_WF2 51604480ull       // 3,072 B
#define OFF_BF2 51607552ull       // 32 B

__device__ __forceinline__ float bflo(u32 v) { return __builtin_bit_cast(float, v << 16); }
__device__ __forceinline__ float bfhi(u32 v) { return __builtin_bit_cast(float, v & 0xffff0000u); }
__device__ __forceinline__ float bf2f(u16 v) { return __builtin_bit_cast(float, ((u32)v) << 16); }
__device__ __forceinline__ u16 f2bf(float f) {
    u32 x = __builtin_bit_cast(u32, f);
    x += 0x7fffu + ((x >> 16) & 1u);   // RNE
    return (u16)(x >> 16);
}
__device__ __forceinline__ u32 pack2(float a, float b) {
    return (u32)f2bf(a) | ((u32)f2bf(b) << 16);
}
__device__ __forceinline__ bool probe_bf16(u32 w0) {
    u32 ex = (w0 >> 7) & 0xFFu;
    bool ok = ((w0 & 0x7FFFu) == 0u) || (ex >= 0x70u && ex <= 0x8Fu);
    return __popcll(__ballot(ok)) >= 48;
}
__device__ __forceinline__ float loadf(const void* p, int i, bool isbf) {
    return isbf ? bf2f(((const u16*)p)[i]) : ((const float*)p)[i];
}

// ---------------- fused preprocessing: param canon + x-cvt + graph bounds + edge scatter ----------------
// blocks [0,8): weight transpose half-tiles; [8,78): param copies;
// [78,12578): x->bf16 (+graph bounds in first 196); [12578,13602): edge binning.
__global__ __launch_bounds__(256) void fused_pre(char* ws, const u32* __restrict__ x,
                                                 u32* __restrict__ xb,
                                                 const int* __restrict__ ei,
                                                 const int* __restrict__ batch,
                                                 int* __restrict__ gstart, int* __restrict__ gend,
                                                 int* __restrict__ binCursor, u32* __restrict__ binned,
                                                 const void* W0, const void* W1,
                                                 const void* W2, const void* W3,
                                                 const void* b0, const void* b1,
                                                 const void* b2, const void* b3,
                                                 const void* Wf1, const void* bf1,
                                                 const void* Wf2, const void* bf2) {
    __shared__ __align__(16) char smem[33024];   // union: prep tile (33,024 B) / scatter (9,324 B)
    int tid = threadIdx.x, lane = tid & 63;
    int b = blockIdx.x;
    if (b < 8) {                                  // transpose W[j] half hf: Wt[n][k] = W[k][n]
        bool isbf = probe_bf16(((const u32*)W0)[lane]);
        int j = b >> 1, hf = b & 1;
        const void* src = (j == 0) ? W0 : (j == 1) ? W1 : (j == 2) ? W2 : W3;
        float* tile = (float*)smem;               // 64 x 129
        for (int it = 0; it < 32; ++it) {
            int idx = it * 256 + tid;             // 0..8191
            int k = idx >> 7, n = idx & 127;
            tile[k * 129 + n] = loadf(src, (hf * 64 + k) * 128 + n, isbf);
        }
        __syncthreads();
        u16* Wt = (u16*)(ws + OFF_WT) + j * 16384;
        for (int it = 0; it < 32; ++it) {
            int o = it * 256 + tid;
            int n = o >> 6, kk = o & 63;
            Wt[n * 128 + hf * 64 + kk] = f2bf(tile[kk * 129 + n]);
        }
        return;
    }
    if (b < 78) {                                 // biases + head params -> fp32
        bool isbf = probe_bf16(((const u32*)W0)[lane]);
        int idx = (b - 8) * 256 + tid;
        float* bc = (float*)(ws + OFF_BC);
        float* Wf1c = (float*)(ws + OFF_WF1);
        float* bf1c = (float*)(ws + OFF_BF1);
        float* Wf2c = (float*)(ws + OFF_WF2);
        float* bf2c = (float*)(ws + OFF_BF2);
        if (idx < 512) {
            int j = idx >> 7, c = idx & 127;
            const void* src = (j == 0) ? b0 : (j == 1) ? b1 : (j == 2) ? b2 : b3;
            bc[idx] = loadf(src, c, isbf);
        } else if (idx < 16896) {
            Wf1c[idx - 512] = loadf(Wf1, idx - 512, isbf);
        } else if (idx < 17024) {
            bf1c[idx - 16896] = loadf(bf1, idx - 16896, isbf);
        } else if (idx < 17792) {
            Wf2c[idx - 17024] = loadf(Wf2, idx - 17024, isbf);
        } else if (idx < 17798) {
            bf2c[idx - 17792] = loadf(bf2, idx - 17792, isbf);
        }
        return;
    }
    if (b < 12578) {                              // x -> packed bf16 (+ graph bounds)
        bool isbf = probe_bf16(x[lane]);
        int bb = b - 78;
        int i = bb * 256 + tid;                   // < 3.2M exactly
        if (isbf) {
            xb[i] = x[i];
        } else {
            float2 v = ((const float2*)x)[i];
            xb[i] = pack2(v.x, v.y);
        }
        if (bb < 196) {
            u32 hiw = ((const u32*)batch)[2 * (12500 + lane) + 1];
            bool i64 = __popcll(__ballot(hiw == 0u)) >= 48;
            int n = bb * 256 + tid;
            if (n < N_NODES) {
                int g = i64 ? batch[2 * n] : batch[n];
                atomicMin(&gstart[g], n);
                atomicMax(&gend[g], n + 1);
            }
        }
        return;
    }
    {                                             // edge binning by dst>>8
        int wg = b - 12578;
        u32* lhist = (u32*)smem;
        u32* lbase = lhist + 256;
        u32* lcur = lbase + 256;
        u32* stash = lcur + 256;                  // ECHUNK u32
        u32 hiw = ((const u32*)ei)[2 * lane + 1];
        bool i64 = __popcll(__ballot(hiw == 0u)) >= 48;
        int e0 = wg * ECHUNK;
        int cnt = N_EDGES - e0; if (cnt > ECHUNK) cnt = ECHUNK; if (cnt < 0) cnt = 0;
        lhist[tid] = 0; lcur[tid] = 0;
        __syncthreads();
        for (int li = tid; li < cnt; li += 256) {
            int e = e0 + li;
            int s, d;
            if (i64) { s = ei[2 * e]; d = ei[2 * N_EDGES + 2 * e]; }
            else     { s = ei[e];     d = ei[N_EDGES + e]; }
            stash[li] = ((u32)d << 16) | (u32)s;
            atomicAdd(&lhist[d >> 8], 1u);
        }
        __syncthreads();
        u32 c = lhist[tid];
        if (c) lbase[tid] = (u32)atomicAdd(&binCursor[tid], (int)c);
        __syncthreads();
        for (int li = tid; li < cnt; li += 256) {
            u32 wv = stash[li];
            int bin = (int)(wv >> 24);
            u32 p = atomicAdd(&lcur[bin], 1u);
            binned[(size_t)bin * BINCAP + lbase[bin] + p] = wv;
        }
    }
}

// ---------------- bucket build from binned edges ----------------
__global__ __launch_bounds__(256) void fill_from_binned(const int* __restrict__ binCursor,
                                                        const u32* __restrict__ binned,
                                                        int* __restrict__ deg,
                                                        u16* __restrict__ bucket) {
    __shared__ u32 ldeg[256];
    int tid = threadIdx.x, b = blockIdx.x;
    int cnt = binCursor[b];
    ldeg[tid] = 0;
    __syncthreads();
    const u32* bp = binned + (size_t)b * BINCAP;
    for (int i = tid; i < cnt; i += 256) {
        u32 w = bp[i];
        u32 dl = (w >> 16) & 255u;
        u32 pos = atomicAdd(&ldeg[dl], 1u);
        if (pos < CAP) bucket[(size_t)(w >> 16) * CAP + pos] = (u16)(w & 0xFFFFu);
    }
    __syncthreads();
    int node = b * 256 + tid;
    if (node < N_NODES) deg[node] = (int)ldeg[tid];
}

// ---------------- aggregation v4: 4 channel-slice passes, L2-resident working set ----------------
// blockIdx slice-major: slice = blk/12500 (all concurrent blocks share a slice phase).
// Per wave: one (node, slice); 16 lanes x 4B = one 64B line per edge; 4 edges via sub-groups.
__global__ __launch_bounds__(256) void agg_kernel(const u32* __restrict__ h,
                                                  const int* __restrict__ deg,
                                                  const u16* __restrict__ bucket,
                                                  u32* __restrict__ out) {
    int w = threadIdx.x >> 6, lane = threadIdx.x & 63;
    int blk = blockIdx.x;
    int slice = blk / 12500;
    int node = (blk % 12500) * 4 + w;            // always < 50000
    int sub = lane >> 4, q = lane & 15;
    int off = slice * 16 + q;
    float ax, ay;
    {
        u32 sv = (sub == 0) ? h[node * 64 + off] : 0u;
        ax = bflo(sv); ay = bfhi(sv);
    }
    int d = deg[node];
    d = d > CAP ? CAP : d;
    const u32* bkw = (const u32*)(bucket + (size_t)node * CAP);
    const u32 sh = (u32)(sub & 1) * 16u;
    const int widx = sub >> 1;
    int j = 0;
    for (; j + 16 <= d; j += 16) {               // 16 edges: 4 independent 64B gathers per lane
        int base = j >> 1;
        u32 wd0 = bkw[base + widx];
        u32 wd1 = bkw[base + 2 + widx];
        u32 wd2 = bkw[base + 4 + widx];
        u32 wd3 = bkw[base + 6 + widx];
        u32 v0 = h[(int)((wd0 >> sh) & 0xFFFFu) * 64 + off];
        u32 v1 = h[(int)((wd1 >> sh) & 0xFFFFu) * 64 + off];
        u32 v2 = h[(int)((wd2 >> sh) & 0xFFFFu) * 64 + off];
        u32 v3 = h[(int)((wd3 >> sh) & 0xFFFFu) * 64 + off];
        ax += bflo(v0) + bflo(v1) + bflo(v2) + bflo(v3);
        ay += bfhi(v0) + bfhi(v1) + bfhi(v2) + bfhi(v3);
    }
    for (; j + 4 <= d; j += 4) {
        u32 wd = bkw[(j >> 1) + widx];
        u32 v = h[(int)((wd >> sh) & 0xFFFFu) * 64 + off];
        ax += bflo(v);
        ay += bfhi(v);
    }
    if (j + sub < d) {
        int e = j + sub;
        u32 wd = bkw[e >> 1];
        u32 id = (wd >> ((u32)(e & 1) * 16u)) & 0xFFFFu;
        u32 v = h[(int)id * 64 + off];
        ax += bflo(v);
        ay += bfhi(v);
    }
    ax += __shfl_xor(ax, 16, 64); ax += __shfl_xor(ax, 32, 64);
    ay += __shfl_xor(ay, 16, 64); ay += __shfl_xor(ay, 32, 64);
    if (sub == 0) out[node * 64 + off] = pack2(ax, ay);
}

// ---------------- fused 2-layer MLP: out = relu(relu(in@Wa+ba)@Wb+bb), bf16 MFMA ----------------
__global__ __launch_bounds__(256) void mlp_kernel(const u16* __restrict__ in,
                                                  const u16* __restrict__ Wta,
                                                  const float* __restrict__ ba,
                                                  const u16* __restrict__ Wtb,
                                                  const float* __restrict__ bb,
                                                  u16* __restrict__ out,
                                                  int nrows) {
    __shared__ __align__(16) u16 Wlds[128 * PAD];
    __shared__ __align__(16) u16 tlds[64 * PAD];
    const int tid = threadIdx.x;
    const int w = tid >> 6;
    const int lane = tid & 63;
    const int n16 = lane & 15;
    const int quad = lane >> 4;
    const int row0 = blockIdx.x * 64 + w * 16;
    const bool active = row0 < nrows;

    {
        const uint4* wsrc = (const uint4*)Wta;
#pragma unroll
        for (int it = 0; it < 8; ++it) {
            int idx = tid + it * 256;
            int n = idx >> 4, c = idx & 15;
            *(uint4*)&Wlds[n * PAD + c * 8] = wsrc[idx];
        }
    }
    __syncthreads();

    f32x4 acc[8];
    bf16x8 afrag[4];
    if (active) {
        const u16* rowp = in + (size_t)(row0 + n16) * CH + quad * 8;
#pragma unroll
        for (int ks = 0; ks < 4; ++ks)
            afrag[ks] = *(const bf16x8*)(rowp + ks * 32);
#pragma unroll
        for (int ct = 0; ct < 8; ++ct) {
            f32x4 a = {0.f, 0.f, 0.f, 0.f};
#pragma unroll
            for (int ks = 0; ks < 4; ++ks) {
                bf16x8 b = *(const bf16x8*)&Wlds[(u32)(ct * 16 + n16) * PAD + ks * 32 + quad * 8];
                a = __builtin_amdgcn_mfma_f32_16x16x32_bf16(afrag[ks], b, a, 0, 0, 0);
            }
            acc[ct] = a;
        }
#pragma unroll
        for (int ct = 0; ct < 8; ++ct) {
            float bv = ba[ct * 16 + n16];
#pragma unroll
            for (int r = 0; r < 4; ++r) {
                float v = fmaxf(acc[ct][r] + bv, 0.f);
                tlds[(w * 16 + quad * 4 + r) * PAD + ct * 16 + n16] = f2bf(v);
            }
        }
    }
    __syncthreads();
    {
        const uint4* wsrc = (const uint4*)Wtb;
#pragma unroll
        for (int it = 0; it < 8; ++it) {
            int idx = tid + it * 256;
            int n = idx >> 4, c = idx & 15;
            *(uint4*)&Wlds[n * PAD + c * 8] = wsrc[idx];
        }
    }
    __syncthreads();

    if (active) {
#pragma unroll
        for (int ks = 0; ks < 4; ++ks)
            afrag[ks] = *(const bf16x8*)&tlds[(u32)(w * 16 + n16) * PAD + ks * 32 + quad * 8];
#pragma unroll
        for (int ct = 0; ct < 8; ++ct) {
            f32x4 a = {0.f, 0.f, 0.f, 0.f};
#pragma unroll
            for (int ks = 0; ks < 4; ++ks) {
                bf16x8 b = *(const bf16x8*)&Wlds[(u32)(ct * 16 + n16) * PAD + ks * 32 + quad * 8];
                a = __builtin_amdgcn_mfma_f32_16x16x32_bf16(afrag[ks], b, a, 0, 0, 0);
            }
            acc[ct] = a;
        }
#pragma unroll
        for (int ct = 0; ct < 8; ++ct) {
            float bv = bb[ct * 16 + n16];
#pragma unroll
            for (int r = 0; r < 4; ++r) {
                float v = fmaxf(acc[ct][r] + bv, 0.f);
                tlds[(w * 16 + quad * 4 + r) * PAD + ct * 16 + n16] = f2bf(v);
            }
        }
        u32* outw = (u32*)out;
        for (int r = 0; r < 16; ++r) {
            u32 v = *(const u32*)&tlds[(w * 16 + r) * PAD + lane * 2];
            outw[(size_t)(row0 + r) * CHW + lane] = v;
        }
    }
}

// ---------------- fused mean-pool + head: one wave per graph ----------------
__global__ __launch_bounds__(256) void pool_final(const u32* __restrict__ h,
                                                  const int* __restrict__ gstart,
                                                  const int* __restrict__ gend,
                                                  const float* __restrict__ Wf1,
                                                  const float* __restrict__ bf1,
                                                  const float* __restrict__ Wf2,
                                                  const float* __restrict__ bf2v,
                                                  float* __restrict__ out) {
    __shared__ float rowb[4][128];
    __shared__ float tb[4][128];
    int w = threadIdx.x >> 6, lane = threadIdx.x & 63;
    int g = blockIdx.x * 4 + w;                  // 128 * 4 = 512 exact
    int sub = lane >> 4, q = lane & 15;
    int s = gstart[g], e = gend[g];
    const uint4* h4 = (const uint4*)h;
    float acc[8] = {0.f, 0.f, 0.f, 0.f, 0.f, 0.f, 0.f, 0.f};
    int i = s + sub;
    for (; i + 4 < e; i += 8) {
        uint4 v0 = h4[(size_t)i * 16 + q];
        uint4 v1 = h4[(size_t)(i + 4) * 16 + q];
        acc[0] += bflo(v0.x) + bflo(v1.x); acc[1] += bfhi(v0.x) + bfhi(v1.x);
        acc[2] += bflo(v0.y) + bflo(v1.y); acc[3] += bfhi(v0.y) + bfhi(v1.y);
        acc[4] += bflo(v0.z) + bflo(v1.z); acc[5] += bfhi(v0.z) + bfhi(v1.z);
        acc[6] += bflo(v0.w) + bflo(v1.w); acc[7] += bfhi(v0.w) + bfhi(v1.w);
    }
    for (; i < e; i += 4) {
        uint4 v = h4[(size_t)i * 16 + q];
        acc[0] += bflo(v.x); acc[1] += bfhi(v.x);
        acc[2] += bflo(v.y); acc[3] += bfhi(v.y);
        acc[4] += bflo(v.z); acc[5] += bfhi(v.z);
        acc[6] += bflo(v.w); acc[7] += bfhi(v.w);
    }
#pragma unroll
    for (int c = 0; c < 8; ++c) {
        acc[c] += __shfl_xor(acc[c], 16, 64);
        acc[c] += __shfl_xor(acc[c], 32, 64);
    }
    if (sub == 0) {
        float inv = 1.f / (float)((e - s) > 0 ? (e - s) : 1);
#pragma unroll
        for (int k = 0; k < 4; ++k) {            // word q*4+k -> channels (q*4+k)*2, +1
            rowb[w][(q * 4 + k) * 2] = acc[2 * k] * inv;
            rowb[w][(q * 4 + k) * 2 + 1] = acc[2 * k + 1] * inv;
        }
    }
    __syncthreads();
#pragma unroll
    for (int jj = 0; jj < 2; ++jj) {
        int jn = lane + jj * 64;
        float a = bf1[jn];
        for (int k = 0; k < 128; ++k) a += rowb[w][k] * Wf1[k * 128 + jn];
        tb[w][jn] = fmaxf(a, 0.f);
    }
    __syncthreads();
    if (lane < 6) {
        float a = bf2v[lane];
        for (int k = 0; k < 128; ++k) a += tb[w][k] * Wf2[k * 6 + lane];
        out[g * 6 + lane] = 1.f / (1.f + __expf(-a));
    }
}

extern "C" void kernel_launch(void* const* d_in, const int* in_sizes, int n_in,
                              void* d_out, int out_size, void* d_ws, size_t ws_size,
                              hipStream_t stream) {
    const u32* x = (const u32*)d_in[0];
    const int* ei = (const int*)d_in[1];
    const int* batch = (const int*)d_in[2];
    float* out = (float*)d_out;

    char* ws = (char*)d_ws;
    int* deg = (int*)(ws + OFF_DEG);
    u16* bucket = (u16*)(ws + OFF_BUCKET);
    u32* XB = (u32*)(ws + OFF_XB);
    u32* HSUM = (u32*)(ws + OFF_HSUM);
    u32* H1 = (u32*)(ws + OFF_H1);
    int* gstart = (int*)(ws + OFF_GS);
    int* gend = (int*)(ws + OFF_GE);
    int* binCursor = (int*)(ws + OFF_BCUR);
    u16* Wt = (u16*)(ws + OFF_WT);
    float* bc = (float*)(ws + OFF_BC);
    float* Wf1c = (float*)(ws + OFF_WF1);
    float* bf1c = (float*)(ws + OFF_BF1);
    float* Wf2c = (float*)(ws + OFF_WF2);
    float* bf2c = (float*)(ws + OFF_BF2);
    u32* binned = HSUM;

    hipMemsetAsync(gend, 0, 3072, stream);       // gend (2KB) + binCursor (1KB), contiguous
    hipMemsetAsync(gstart, 0x7F, 2048, stream);

    fused_pre<<<13602, 256, 0, stream>>>(ws, x, XB, ei, batch, gstart, gend, binCursor, binned,
        d_in[3], d_in[5], d_in[7], d_in[9],      // W1a, W1b, W2a, W2b
        d_in[4], d_in[6], d_in[8], d_in[10],     // b1a, b1b, b2a, b2b
        d_in[11], d_in[12], d_in[13], d_in[14]); // Wf1, bf1, Wf2, bf2
    fill_from_binned<<<NBINS, 256, 0, stream>>>(binCursor, binned, deg, bucket);

    // layer 1: XB -> HSUM -> H1   (binned consumed; HSUM safely overwritten)
    agg_kernel<<<50000, 256, 0, stream>>>(XB, deg, bucket, HSUM);
    mlp_kernel<<<(N_NODES + 63) / 64, 256, 0, stream>>>((const u16*)HSUM, Wt, bc,
                                                        Wt + 16384, bc + 128, (u16*)H1, N_NODES);
    // layer 2: H1 -> HSUM -> XB (reused as h2)
    agg_kernel<<<50000, 256, 0, stream>>>(H1, deg, bucket, HSUM);
    mlp_kernel<<<(N_NODES + 63) / 64, 256, 0, stream>>>((const u16*)HSUM, Wt + 32768, bc + 256,
                                                        Wt + 49152, bc + 384, (u16*)XB, N_NODES);
    // fused pool + head
    pool_final<<<NG / 4, 256, 0, stream>>>(XB, gstart, gend, Wf1c, bf1c, Wf2c, bf2c, out);
}

// Round 15
// 309.587 us; speedup vs baseline: 1.3283x; 1.3283x over previous
//
#include <hip/hip_runtime.h>

typedef unsigned short u16;
typedef unsigned int u32;

#define N_NODES 50000
#define N_EDGES 1600000
#define CH 128
#define CHW 64          // u32 words per packed-bf16 row
#define NG 512
#define CAP 128         // bucket capacity per node (Poisson(32): P(>=128) ~ 1e-43)
#define PAD 136         // LDS row stride in bf16 elems (272B: 16B-aligned, bank-spread)
#define NBINS 196       // ceil(50000/256)
#define BINCAP 12288    // slots per bin (expect ~8192, max ~8650)
#define ECHUNK 1563     // edges per scatter WG (1024*1563 >= 1.6M)

typedef __bf16 bf16x8 __attribute__((ext_vector_type(8)));
typedef float f32x4 __attribute__((ext_vector_type(4)));

// ---- workspace byte offsets (total ~51.6 MB) ----
#define OFF_DEG 0ull
#define OFF_BUCKET 200192ull      // u16 bucket, 12,800,000 B
#define OFF_XB 13000192ull        // 12.8 MB packed-bf16 x; reused as h2
#define OFF_HSUM 25800192ull      // 12.8 MB; binned edges (9.6 MB) overlap pre-agg
#define OFF_H1 38600192ull        // 12.8 MB
#define OFF_GS 51400192ull        // 2,048 B
#define OFF_GE 51402240ull        // 2,048 B (gend + binCursor contiguous: one memset)
#define OFF_BCUR 51404288ull      // 1,024 B
#define OFF_WT 51405312ull        // 4 x 32,768 B bf16 transposed weights [n][k]
#define OFF_BC 51536384ull        // 4 x 512 B fp32 biases
#define OFF_WF1 51538432ull       // 65,536 B fp32
#define OFF_BF1 51603968ull       // 512 B
#define OFF_WF2 51604480ull       // 3,072 B
#define OFF_BF2 51607552ull       // 32 B

__device__ __forceinline__ float bflo(u32 v) { return __builtin_bit_cast(float, v << 16); }
__device__ __forceinline__ float bfhi(u32 v) { return __builtin_bit_cast(float, v & 0xffff0000u); }
__device__ __forceinline__ float bf2f(u16 v) { return __builtin_bit_cast(float, ((u32)v) << 16); }
__device__ __forceinline__ u16 f2bf(float f) {
    u32 x = __builtin_bit_cast(u32, f);
    x += 0x7fffu + ((x >> 16) & 1u);   // RNE
    return (u16)(x >> 16);
}
__device__ __forceinline__ u32 pack2(float a, float b) {
    return (u32)f2bf(a) | ((u32)f2bf(b) << 16);
}
__device__ __forceinline__ bool probe_bf16(u32 w0) {
    u32 ex = (w0 >> 7) & 0xFFu;
    bool ok = ((w0 & 0x7FFFu) == 0u) || (ex >= 0x70u && ex <= 0x8Fu);
    return __popcll(__ballot(ok)) >= 48;
}
__device__ __forceinline__ float loadf(const void* p, int i, bool isbf) {
    return isbf ? bf2f(((const u16*)p)[i]) : ((const float*)p)[i];
}

// ---------------- fused preprocessing: param canon + x-cvt + graph bounds + edge scatter ----------------
__global__ __launch_bounds__(256) void fused_pre(char* ws, const u32* __restrict__ x,
                                                 u32* __restrict__ xb,
                                                 const int* __restrict__ ei,
                                                 const int* __restrict__ batch,
                                                 int* __restrict__ gstart, int* __restrict__ gend,
                                                 int* __restrict__ binCursor, u32* __restrict__ binned,
                                                 const void* W0, const void* W1,
                                                 const void* W2, const void* W3,
                                                 const void* b0, const void* b1,
                                                 const void* b2, const void* b3,
                                                 const void* Wf1, const void* bf1,
                                                 const void* Wf2, const void* bf2) {
    __shared__ __align__(16) char smem[33024];   // union: prep tile (33,024 B) / scatter (9,324 B)
    int tid = threadIdx.x, lane = tid & 63;
    int b = blockIdx.x;
    if (b < 8) {                                  // transpose W[j] half hf: Wt[n][k] = W[k][n]
        bool isbf = probe_bf16(((const u32*)W0)[lane]);
        int j = b >> 1, hf = b & 1;
        const void* src = (j == 0) ? W0 : (j == 1) ? W1 : (j == 2) ? W2 : W3;
        float* tile = (float*)smem;               // 64 x 129
        for (int it = 0; it < 32; ++it) {
            int idx = it * 256 + tid;             // 0..8191
            int k = idx >> 7, n = idx & 127;
            tile[k * 129 + n] = loadf(src, (hf * 64 + k) * 128 + n, isbf);
        }
        __syncthreads();
        u16* Wt = (u16*)(ws + OFF_WT) + j * 16384;
        for (int it = 0; it < 32; ++it) {
            int o = it * 256 + tid;
            int n = o >> 6, kk = o & 63;
            Wt[n * 128 + hf * 64 + kk] = f2bf(tile[kk * 129 + n]);
        }
        return;
    }
    if (b < 78) {                                 // biases + head params -> fp32
        bool isbf = probe_bf16(((const u32*)W0)[lane]);
        int idx = (b - 8) * 256 + tid;
        float* bc = (float*)(ws + OFF_BC);
        float* Wf1c = (float*)(ws + OFF_WF1);
        float* bf1c = (float*)(ws + OFF_BF1);
        float* Wf2c = (float*)(ws + OFF_WF2);
        float* bf2c = (float*)(ws + OFF_BF2);
        if (idx < 512) {
            int j = idx >> 7, c = idx & 127;
            const void* src = (j == 0) ? b0 : (j == 1) ? b1 : (j == 2) ? b2 : b3;
            bc[idx] = loadf(src, c, isbf);
        } else if (idx < 16896) {
            Wf1c[idx - 512] = loadf(Wf1, idx - 512, isbf);
        } else if (idx < 17024) {
            bf1c[idx - 16896] = loadf(bf1, idx - 16896, isbf);
        } else if (idx < 17792) {
            Wf2c[idx - 17024] = loadf(Wf2, idx - 17024, isbf);
        } else if (idx < 17798) {
            bf2c[idx - 17792] = loadf(bf2, idx - 17792, isbf);
        }
        return;
    }
    if (b < 12578) {                              // x -> packed bf16 (+ graph bounds)
        bool isbf = probe_bf16(x[lane]);
        int bb = b - 78;
        int i = bb * 256 + tid;                   // < 3.2M exactly
        if (isbf) {
            xb[i] = x[i];
        } else {
            float2 v = ((const float2*)x)[i];
            xb[i] = pack2(v.x, v.y);
        }
        if (bb < 196) {
            u32 hiw = ((const u32*)batch)[2 * (12500 + lane) + 1];
            bool i64 = __popcll(__ballot(hiw == 0u)) >= 48;
            int n = bb * 256 + tid;
            if (n < N_NODES) {
                int g = i64 ? batch[2 * n] : batch[n];
                atomicMin(&gstart[g], n);
                atomicMax(&gend[g], n + 1);
            }
        }
        return;
    }
    {                                             // edge binning by dst>>8
        int wg = b - 12578;
        u32* lhist = (u32*)smem;
        u32* lbase = lhist + 256;
        u32* lcur = lbase + 256;
        u32* stash = lcur + 256;                  // ECHUNK u32
        u32 hiw = ((const u32*)ei)[2 * lane + 1];
        bool i64 = __popcll(__ballot(hiw == 0u)) >= 48;
        int e0 = wg * ECHUNK;
        int cnt = N_EDGES - e0; if (cnt > ECHUNK) cnt = ECHUNK; if (cnt < 0) cnt = 0;
        lhist[tid] = 0; lcur[tid] = 0;
        __syncthreads();
        for (int li = tid; li < cnt; li += 256) {
            int e = e0 + li;
            int s, d;
            if (i64) { s = ei[2 * e]; d = ei[2 * N_EDGES + 2 * e]; }
            else     { s = ei[e];     d = ei[N_EDGES + e]; }
            stash[li] = ((u32)d << 16) | (u32)s;
            atomicAdd(&lhist[d >> 8], 1u);
        }
        __syncthreads();
        u32 c = lhist[tid];
        if (c) lbase[tid] = (u32)atomicAdd(&binCursor[tid], (int)c);
        __syncthreads();
        for (int li = tid; li < cnt; li += 256) {
            u32 wv = stash[li];
            int bin = (int)(wv >> 24);
            u32 p = atomicAdd(&lcur[bin], 1u);
            binned[(size_t)bin * BINCAP + lbase[bin] + p] = wv;
        }
    }
}

// ---------------- bucket build from binned edges ----------------
__global__ __launch_bounds__(256) void fill_from_binned(const int* __restrict__ binCursor,
                                                        const u32* __restrict__ binned,
                                                        int* __restrict__ deg,
                                                        u16* __restrict__ bucket) {
    __shared__ u32 ldeg[256];
    int tid = threadIdx.x, b = blockIdx.x;
    int cnt = binCursor[b];
    ldeg[tid] = 0;
    __syncthreads();
    const u32* bp = binned + (size_t)b * BINCAP;
    for (int i = tid; i < cnt; i += 256) {
        u32 w = bp[i];
        u32 dl = (w >> 16) & 255u;
        u32 pos = atomicAdd(&ldeg[dl], 1u);
        if (pos < CAP) bucket[(size_t)(w >> 16) * CAP + pos] = (u16)(w & 0xFFFFu);
    }
    __syncthreads();
    int node = b * 256 + tid;
    if (node < N_NODES) deg[node] = (int)ldeg[tid];
}

// ---------------- aggregation (R12-v2, best measured): uint4 gathers, 16-edge tier ----------------
__global__ __launch_bounds__(256) void agg_kernel(const u32* __restrict__ h,
                                                  const int* __restrict__ deg,
                                                  const u16* __restrict__ bucket,
                                                  u32* __restrict__ out) {
    int w = threadIdx.x >> 6, lane = threadIdx.x & 63;
    int node = blockIdx.x * 4 + w;
    if (node >= N_NODES) return;
    int sub = lane >> 4, q = lane & 15;
    const uint4* h4 = (const uint4*)h;
    float acc[8];
    {   // self row, counted once (sub 0 only)
        uint4 sv = make_uint4(0u, 0u, 0u, 0u);
        if (sub == 0) sv = h4[(size_t)node * 16 + q];
        acc[0] = bflo(sv.x); acc[1] = bfhi(sv.x);
        acc[2] = bflo(sv.y); acc[3] = bfhi(sv.y);
        acc[4] = bflo(sv.z); acc[5] = bfhi(sv.z);
        acc[6] = bflo(sv.w); acc[7] = bfhi(sv.w);
    }
    int d = deg[node];
    d = d > CAP ? CAP : d;
    const u32* bkw = (const u32*)(bucket + (size_t)node * CAP);
    const u32 sh = (u32)(sub & 1) * 16u;
    const int widx = sub >> 1;
    int j = 0;
    for (; j + 16 <= d; j += 16) {           // 16 edges: 4 independent 4-row gathers in flight
        int base = j >> 1;
        u32 wd0 = bkw[base + widx];
        u32 wd1 = bkw[base + 2 + widx];
        u32 wd2 = bkw[base + 4 + widx];
        u32 wd3 = bkw[base + 6 + widx];
        uint4 v0 = h4[(size_t)((wd0 >> sh) & 0xFFFFu) * 16 + q];
        uint4 v1 = h4[(size_t)((wd1 >> sh) & 0xFFFFu) * 16 + q];
        uint4 v2 = h4[(size_t)((wd2 >> sh) & 0xFFFFu) * 16 + q];
        uint4 v3 = h4[(size_t)((wd3 >> sh) & 0xFFFFu) * 16 + q];
        acc[0] += bflo(v0.x) + bflo(v1.x) + bflo(v2.x) + bflo(v3.x);
        acc[1] += bfhi(v0.x) + bfhi(v1.x) + bfhi(v2.x) + bfhi(v3.x);
        acc[2] += bflo(v0.y) + bflo(v1.y) + bflo(v2.y) + bflo(v3.y);
        acc[3] += bfhi(v0.y) + bfhi(v1.y) + bfhi(v2.y) + bfhi(v3.y);
        acc[4] += bflo(v0.z) + bflo(v1.z) + bflo(v2.z) + bflo(v3.z);
        acc[5] += bfhi(v0.z) + bfhi(v1.z) + bfhi(v2.z) + bfhi(v3.z);
        acc[6] += bflo(v0.w) + bflo(v1.w) + bflo(v2.w) + bflo(v3.w);
        acc[7] += bfhi(v0.w) + bfhi(v1.w) + bfhi(v2.w) + bfhi(v3.w);
    }
    for (; j + 4 <= d; j += 4) {             // 4-edge groups
        u32 wd = bkw[(j >> 1) + widx];
        uint4 v = h4[(size_t)((wd >> sh) & 0xFFFFu) * 16 + q];
        acc[0] += bflo(v.x); acc[1] += bfhi(v.x);
        acc[2] += bflo(v.y); acc[3] += bfhi(v.y);
        acc[4] += bflo(v.z); acc[5] += bfhi(v.z);
        acc[6] += bflo(v.w); acc[7] += bfhi(v.w);
    }
    if (j + sub < d) {                       // tail (<4 edges), predicated per sub
        int e = j + sub;
        u32 wd = bkw[e >> 1];
        u32 id = (wd >> ((u32)(e & 1) * 16u)) & 0xFFFFu;
        uint4 v = h4[(size_t)id * 16 + q];
        acc[0] += bflo(v.x); acc[1] += bfhi(v.x);
        acc[2] += bflo(v.y); acc[3] += bfhi(v.y);
        acc[4] += bflo(v.z); acc[5] += bfhi(v.z);
        acc[6] += bflo(v.w); acc[7] += bfhi(v.w);
    }
#pragma unroll
    for (int c = 0; c < 8; ++c) {            // butterfly across the 4 sub-groups
        acc[c] += __shfl_xor(acc[c], 16, 64);
        acc[c] += __shfl_xor(acc[c], 32, 64);
    }
    if (sub == 0) {                          // 16 lanes x 16B = one contiguous 256B row
        uint4 o;
        o.x = pack2(acc[0], acc[1]);
        o.y = pack2(acc[2], acc[3]);
        o.z = pack2(acc[4], acc[5]);
        o.w = pack2(acc[6], acc[7]);
        ((uint4*)out)[(size_t)node * 16 + q] = o;
    }
}

// ---------------- fused 2-layer MLP: out = relu(relu(in@Wa+ba)@Wb+bb), bf16 MFMA ----------------
__global__ __launch_bounds__(256) void mlp_kernel(const u16* __restrict__ in,
                                                  const u16* __restrict__ Wta,
                                                  const float* __restrict__ ba,
                                                  const u16* __restrict__ Wtb,
                                                  const float* __restrict__ bb,
                                                  u16* __restrict__ out,
                                                  int nrows) {
    __shared__ __align__(16) u16 Wlds[128 * PAD];
    __shared__ __align__(16) u16 tlds[64 * PAD];
    const int tid = threadIdx.x;
    const int w = tid >> 6;
    const int lane = tid & 63;
    const int n16 = lane & 15;
    const int quad = lane >> 4;
    const int row0 = blockIdx.x * 64 + w * 16;
    const bool active = row0 < nrows;

    {
        const uint4* wsrc = (const uint4*)Wta;
#pragma unroll
        for (int it = 0; it < 8; ++it) {
            int idx = tid + it * 256;
            int n = idx >> 4, c = idx & 15;
            *(uint4*)&Wlds[n * PAD + c * 8] = wsrc[idx];
        }
    }
    __syncthreads();

    f32x4 acc[8];
    bf16x8 afrag[4];
    if (active) {
        const u16* rowp = in + (size_t)(row0 + n16) * CH + quad * 8;
#pragma unroll
        for (int ks = 0; ks < 4; ++ks)
            afrag[ks] = *(const bf16x8*)(rowp + ks * 32);
#pragma unroll
        for (int ct = 0; ct < 8; ++ct) {
            f32x4 a = {0.f, 0.f, 0.f, 0.f};
#pragma unroll
            for (int ks = 0; ks < 4; ++ks) {
                bf16x8 b = *(const bf16x8*)&Wlds[(u32)(ct * 16 + n16) * PAD + ks * 32 + quad * 8];
                a = __builtin_amdgcn_mfma_f32_16x16x32_bf16(afrag[ks], b, a, 0, 0, 0);
            }
            acc[ct] = a;
        }
#pragma unroll
        for (int ct = 0; ct < 8; ++ct) {
            float bv = ba[ct * 16 + n16];
#pragma unroll
            for (int r = 0; r < 4; ++r) {
                float v = fmaxf(acc[ct][r] + bv, 0.f);
                tlds[(w * 16 + quad * 4 + r) * PAD + ct * 16 + n16] = f2bf(v);
            }
        }
    }
    __syncthreads();
    {
        const uint4* wsrc = (const uint4*)Wtb;
#pragma unroll
        for (int it = 0; it < 8; ++it) {
            int idx = tid + it * 256;
            int n = idx >> 4, c = idx & 15;
            *(uint4*)&Wlds[n * PAD + c * 8] = wsrc[idx];
        }
    }
    __syncthreads();

    if (active) {
#pragma unroll
        for (int ks = 0; ks < 4; ++ks)
            afrag[ks] = *(const bf16x8*)&tlds[(u32)(w * 16 + n16) * PAD + ks * 32 + quad * 8];
#pragma unroll
        for (int ct = 0; ct < 8; ++ct) {
            f32x4 a = {0.f, 0.f, 0.f, 0.f};
#pragma unroll
            for (int ks = 0; ks < 4; ++ks) {
                bf16x8 b = *(const bf16x8*)&Wlds[(u32)(ct * 16 + n16) * PAD + ks * 32 + quad * 8];
                a = __builtin_amdgcn_mfma_f32_16x16x32_bf16(afrag[ks], b, a, 0, 0, 0);
            }
            acc[ct] = a;
        }
#pragma unroll
        for (int ct = 0; ct < 8; ++ct) {
            float bv = bb[ct * 16 + n16];
#pragma unroll
            for (int r = 0; r < 4; ++r) {
                float v = fmaxf(acc[ct][r] + bv, 0.f);
                tlds[(w * 16 + quad * 4 + r) * PAD + ct * 16 + n16] = f2bf(v);
            }
        }
        u32* outw = (u32*)out;
        for (int r = 0; r < 16; ++r) {
            u32 v = *(const u32*)&tlds[(w * 16 + r) * PAD + lane * 2];
            outw[(size_t)(row0 + r) * CHW + lane] = v;
        }
    }
}

// ---------------- fused mean-pool + head: one wave per graph ----------------
__global__ __launch_bounds__(256) void pool_final(const u32* __restrict__ h,
                                                  const int* __restrict__ gstart,
                                                  const int* __restrict__ gend,
                                                  const float* __restrict__ Wf1,
                                                  const float* __restrict__ bf1,
                                                  const float* __restrict__ Wf2,
                                                  const float* __restrict__ bf2v,
                                                  float* __restrict__ out) {
    __shared__ float rowb[4][128];
    __shared__ float tb[4][128];
    int w = threadIdx.x >> 6, lane = threadIdx.x & 63;
    int g = blockIdx.x * 4 + w;                  // 128 * 4 = 512 exact
    int sub = lane >> 4, q = lane & 15;
    int s = gstart[g], e = gend[g];
    const uint4* h4 = (const uint4*)h;
    float acc[8] = {0.f, 0.f, 0.f, 0.f, 0.f, 0.f, 0.f, 0.f};
    int i = s + sub;
    for (; i + 4 < e; i += 8) {
        uint4 v0 = h4[(size_t)i * 16 + q];
        uint4 v1 = h4[(size_t)(i + 4) * 16 + q];
        acc[0] += bflo(v0.x) + bflo(v1.x); acc[1] += bfhi(v0.x) + bfhi(v1.x);
        acc[2] += bflo(v0.y) + bflo(v1.y); acc[3] += bfhi(v0.y) + bfhi(v1.y);
        acc[4] += bflo(v0.z) + bflo(v1.z); acc[5] += bfhi(v0.z) + bfhi(v1.z);
        acc[6] += bflo(v0.w) + bflo(v1.w); acc[7] += bfhi(v0.w) + bfhi(v1.w);
    }
    for (; i < e; i += 4) {
        uint4 v = h4[(size_t)i * 16 + q];
        acc[0] += bflo(v.x); acc[1] += bfhi(v.x);
        acc[2] += bflo(v.y); acc[3] += bfhi(v.y);
        acc[4] += bflo(v.z); acc[5] += bfhi(v.z);
        acc[6] += bflo(v.w); acc[7] += bfhi(v.w);
    }
#pragma unroll
    for (int c = 0; c < 8; ++c) {
        acc[c] += __shfl_xor(acc[c], 16, 64);
        acc[c] += __shfl_xor(acc[c], 32, 64);
    }
    if (sub == 0) {
        float inv = 1.f / (float)((e - s) > 0 ? (e - s) : 1);
#pragma unroll
        for (int k = 0; k < 4; ++k) {            // word q*4+k -> channels (q*4+k)*2, +1
            rowb[w][(q * 4 + k) * 2] = acc[2 * k] * inv;
            rowb[w][(q * 4 + k) * 2 + 1] = acc[2 * k + 1] * inv;
        }
    }
    __syncthreads();
#pragma unroll
    for (int jj = 0; jj < 2; ++jj) {
        int jn = lane + jj * 64;
        float a = bf1[jn];
        for (int k = 0; k < 128; ++k) a += rowb[w][k] * Wf1[k * 128 + jn];
        tb[w][jn] = fmaxf(a, 0.f);
    }
    __syncthreads();
    if (lane < 6) {
        float a = bf2v[lane];
        for (int k = 0; k < 128; ++k) a += tb[w][k] * Wf2[k * 6 + lane];
        out[g * 6 + lane] = 1.f / (1.f + __expf(-a));
    }
}

extern "C" void kernel_launch(void* const* d_in, const int* in_sizes, int n_in,
                              void* d_out, int out_size, void* d_ws, size_t ws_size,
                              hipStream_t stream) {
    const u32* x = (const u32*)d_in[0];
    const int* ei = (const int*)d_in[1];
    const int* batch = (const int*)d_in[2];
    float* out = (float*)d_out;

    char* ws = (char*)d_ws;
    int* deg = (int*)(ws + OFF_DEG);
    u16* bucket = (u16*)(ws + OFF_BUCKET);
    u32* XB = (u32*)(ws + OFF_XB);
    u32* HSUM = (u32*)(ws + OFF_HSUM);
    u32* H1 = (u32*)(ws + OFF_H1);
    int* gstart = (int*)(ws + OFF_GS);
    int* gend = (int*)(ws + OFF_GE);
    int* binCursor = (int*)(ws + OFF_BCUR);
    u16* Wt = (u16*)(ws + OFF_WT);
    float* bc = (float*)(ws + OFF_BC);
    float* Wf1c = (float*)(ws + OFF_WF1);
    float* bf1c = (float*)(ws + OFF_BF1);
    float* Wf2c = (float*)(ws + OFF_WF2);
    float* bf2c = (float*)(ws + OFF_BF2);
    u32* binned = HSUM;

    hipMemsetAsync(gend, 0, 3072, stream);       // gend (2KB) + binCursor (1KB), contiguous
    hipMemsetAsync(gstart, 0x7F, 2048, stream);

    fused_pre<<<13602, 256, 0, stream>>>(ws, x, XB, ei, batch, gstart, gend, binCursor, binned,
        d_in[3], d_in[5], d_in[7], d_in[9],      // W1a, W1b, W2a, W2b
        d_in[4], d_in[6], d_in[8], d_in[10],     // b1a, b1b, b2a, b2b
        d_in[11], d_in[12], d_in[13], d_in[14]); // Wf1, bf1, Wf2, bf2
    fill_from_binned<<<NBINS, 256, 0, stream>>>(binCursor, binned, deg, bucket);

    // layer 1: XB -> HSUM -> H1   (binned consumed; HSUM safely overwritten)
    agg_kernel<<<(N_NODES + 3) / 4, 256, 0, stream>>>(XB, deg, bucket, HSUM);
    mlp_kernel<<<(N_NODES + 63) / 64, 256, 0, stream>>>((const u16*)HSUM, Wt, bc,
                                                        Wt + 16384, bc + 128, (u16*)H1, N_NODES);
    // layer 2: H1 -> HSUM -> XB (reused as h2)
    agg_kernel<<<(N_NODES + 3) / 4, 256, 0, stream>>>(H1, deg, bucket, HSUM);
    mlp_kernel<<<(N_NODES + 63) / 64, 256, 0, stream>>>((const u16*)HSUM, Wt + 32768, bc + 256,
                                                        Wt + 49152, bc + 384, (u16*)XB, N_NODES);
    // fused pool + head
    pool_final<<<NG / 4, 256, 0, stream>>>(XB, gstart, gend, Wf1c, bf1c, Wf2c, bf2c, out);
}